// Round 6
// baseline (214.688 us; speedup 1.0000x reference)
//
#include <hip/hip_runtime.h>
#include <hip/hip_bf16.h>

#define NB 4
#define NN 2048
#define FIN 64
#define DOUT 128

typedef __hip_bfloat16 bf16;
typedef __attribute__((ext_vector_type(8))) short short8;
typedef __attribute__((ext_vector_type(4))) float f32x4;
typedef __attribute__((ext_vector_type(4))) int int4v;

static __device__ __forceinline__ float bf2f(bf16 v) { return __bfloat162float(v); }
static __device__ __forceinline__ bf16  f2bf(float v) { return __float2bfloat16(v); }
static __device__ __forceinline__ unsigned bfbits(float v) {
    bf16 h = __float2bfloat16(v);
    return (unsigned)*reinterpret_cast<unsigned short*>(&h);
}

// vT layout (R2, kept): [b][key/64][dim 0..127][key%64] (bf16), dense 128B rows.
#define VT_IDX(b, key, d) ((((size_t)(b)*32 + ((key) >> 6))*128 + (d))*64 + ((key) & 63))

// ---------------- Kernel 1: q1,k1 (bf16), vT (bf16), proj (fp32) ----------------
__global__ __launch_bounds__(256) void k_gemm1(
    const float* __restrict__ x,
    const float* __restrict__ q1w, const float* __restrict__ q1b,
    const float* __restrict__ k1w, const float* __restrict__ k1b,
    const float* __restrict__ v1w, const float* __restrict__ v1b,
    const float* __restrict__ pw,
    bf16* __restrict__ qA, bf16* __restrict__ kA, bf16* __restrict__ vT,
    float* __restrict__ proj)
{
    __shared__ float At[64][65];
    __shared__ float Wt[64][65];
    const int rb = blockIdx.x;
    const int cb = blockIdx.y;
    const int mat = cb >> 1;
    const int c0 = (cb & 1) * 64;
    const float* W    = (mat==0)? q1w : (mat==1)? k1w : (mat==2)? v1w : pw;
    const float* bias = (mat==0)? q1b : (mat==1)? k1b : (mat==2)? v1b : nullptr;
    const int t = threadIdx.x;
    const int row0 = rb * 64;
    for (int e = t; e < 64*64; e += 256) {
        int r = e >> 6, c = e & 63;
        At[r][c] = x[(size_t)(row0 + r)*FIN + c];
        Wt[r][c] = W[r*DOUT + c0 + c];
    }
    __syncthreads();
    const int ty = t >> 4, tx = t & 15;
    float acc[4][4] = {};
    #pragma unroll 8
    for (int k = 0; k < 64; ++k) {
        float av[4], bv[4];
        #pragma unroll
        for (int i = 0; i < 4; ++i) av[i] = At[ty*4+i][k];
        #pragma unroll
        for (int j = 0; j < 4; ++j) bv[j] = Wt[k][tx*4+j];
        #pragma unroll
        for (int i = 0; i < 4; ++i)
            #pragma unroll
            for (int j = 0; j < 4; ++j)
                acc[i][j] = fmaf(av[i], bv[j], acc[i][j]);
    }
    #pragma unroll
    for (int i = 0; i < 4; ++i) {
        int gr = row0 + ty*4 + i;
        #pragma unroll
        for (int j = 0; j < 4; ++j) {
            int gc = c0 + tx*4 + j;
            float v = acc[i][j] + (bias ? bias[gc] : 0.f);
            if (mat == 0)      qA[(size_t)gr*DOUT + gc] = f2bf(v);
            else if (mat == 1) kA[(size_t)gr*DOUT + gc] = f2bf(v);
            else if (mat == 2) {
                int b = gr >> 11, n = gr & 2047;
                vT[VT_IDX(b, n, gc)] = f2bf(v);
            } else proj[(size_t)gr*DOUT + gc] = v;
        }
    }
}

// ---------------- Kernel 3: q2,k2 (bf16), vT = h @ W (+bias) ----------------
__global__ __launch_bounds__(256) void k_gemm2(
    const bf16* __restrict__ h,
    const float* __restrict__ q2w, const float* __restrict__ q2b,
    const float* __restrict__ k2w, const float* __restrict__ k2b,
    const float* __restrict__ v2w, const float* __restrict__ v2b,
    bf16* __restrict__ qA, bf16* __restrict__ kA, bf16* __restrict__ vT)
{
    __shared__ float At[64][65];
    __shared__ float Wt[64][65];
    const int rb = blockIdx.x, cb = blockIdx.y;
    const int mat = cb >> 1, c0 = (cb & 1)*64;
    const float* W    = (mat==0)? q2w : (mat==1)? k2w : v2w;
    const float* bias = (mat==0)? q2b : (mat==1)? k2b : v2b;
    const int t = threadIdx.x, ty = t >> 4, tx = t & 15, row0 = rb*64;
    float acc[4][4] = {};
    for (int kc = 0; kc < 2; ++kc) {
        __syncthreads();
        for (int e = t; e < 64*64; e += 256) {
            int r = e >> 6, c = e & 63;
            At[r][c] = bf2f(h[(size_t)(row0+r)*DOUT + kc*64 + c]);
            Wt[r][c] = W[(kc*64+r)*DOUT + c0 + c];
        }
        __syncthreads();
        #pragma unroll 8
        for (int k = 0; k < 64; ++k) {
            float av[4], bv[4];
            #pragma unroll
            for (int i = 0; i < 4; ++i) av[i] = At[ty*4+i][k];
            #pragma unroll
            for (int j = 0; j < 4; ++j) bv[j] = Wt[k][tx*4+j];
            #pragma unroll
            for (int i = 0; i < 4; ++i)
                #pragma unroll
                for (int j = 0; j < 4; ++j)
                    acc[i][j] = fmaf(av[i], bv[j], acc[i][j]);
        }
    }
    #pragma unroll
    for (int i = 0; i < 4; ++i) {
        int gr = row0 + ty*4 + i;
        #pragma unroll
        for (int j = 0; j < 4; ++j) {
            int gc = c0 + tx*4 + j;
            float v = acc[i][j] + bias[gc];
            if (mat == 0)      qA[(size_t)gr*DOUT + gc] = f2bf(v);
            else if (mat == 1) kA[(size_t)gr*DOUT + gc] = f2bf(v);
            else {
                int b = gr >> 11, n = gr & 2047;
                vT[VT_IDX(b, n, gc)] = f2bf(v);
            }
        }
    }
}

// ---------------- MFMA flash attention v6: NQ=4 query-tiles per block ----------------
// Confirmed model (r5 HIT): attention cost = F + u*traffic with F~15us, u~25us/256MB
// of scattered 64B cache requests; all pipes idle -> request-rate wall. NQ=2 halved
// traffic and won -52us. NQ=4 halves it again (512->128MB total per attn kernel).
// MODE 1 register budget: qf(64)+acc(128)=192 persistent; score/PV halves are
// interleaved (scores mt{0,1} -> PV ks2=0 -> scores mt{2,3} -> PV ks2=1) to cap
// transient liveness ~250 < 256 VGPR (launch_bounds min 2 waves/EU). MODE1 grid is
// 128 blocks (half CUs) -> also an A/B: shared-wall predicts ~27us, per-CU ~40us.
// MODE 0: relu -> h bf16 (gat1, D=32, H=4). MODE 1: +proj residual + LayerNorm -> fp32.
template<int D, int MODE, int NW, int NQ>
__global__ __launch_bounds__(NW*64, 2) void k_attn_mfma(
    const bf16* __restrict__ qA, const bf16* __restrict__ kA, const bf16* __restrict__ vT,
    const float* __restrict__ proj, const float* __restrict__ lng, const float* __restrict__ lnb,
    bf16* __restrict__ hout, float* __restrict__ fout)
{
    constexpr int NKS = D / 32;     // 32-dim k-steps in S^T
    constexpr int NMT = D / 16;     // 16-dim m-tiles of O^T
    constexpr int ITERS = NN / (64 * NW);

    __shared__ float lbuf[NW][NQ*16];
    constexpr int OSW = (MODE == 0) ? (D + 1) : (D + 2);
    __shared__ char oS_raw[(size_t)NW * NQ*16 * OSW * ((MODE == 0) ? 4 : 2)];

    const float scale = (D == 32) ? 0.17677669529663687f : 0.08838834764831843f;

    // XCD-aware swizzle (xcd = linear_wg % 8).
    const unsigned wg  = blockIdx.x + (unsigned)gridDim.x * blockIdx.y;
    const unsigned xcd = wg & 7u;
    const unsigned idx = wg >> 3;
    int qb, bh;
    if constexpr (MODE == 0) {
        // 512 wgs: idx 0..63. 2 adjacent heads per XCD; 32 q-blocks.
        bh = (int)((xcd << 1) | (idx >> 5));   // 0..15
        qb = (int)(idx & 31u);                 // 0..31
    } else {
        // 128 wgs: idx 0..15. 1 batch per XCD-pair; 32 q-blocks.
        bh = (int)(xcd >> 1);                  // 0..3
        qb = (int)(((xcd & 1u) << 4) | idx);   // 0..31
    }

    const int b  = (MODE == 0) ? (bh >> 2) : bh;
    const int hd = (MODE == 0) ? (bh & 3) : 0;
    const int q0 = qb * (16*NQ);
    const int wave = threadIdx.x >> 6, lane = threadIdx.x & 63;
    const int n16 = lane & 15, q4 = lane >> 4;

    const short* qbase = (const short*)qA + ((size_t)b*NN)*DOUT + hd*32;
    const short* kbase = (const short*)kA + ((size_t)b*NN)*DOUT + hd*32;
    const short* vbase = (const short*)vT + (size_t)b*32*128*64 + (size_t)(hd*32)*64;

    // Q B-fragments for each of the NQ query tiles — held in regs
    short8 qf[NQ][NKS];
    #pragma unroll
    for (int qq = 0; qq < NQ; ++qq)
        #pragma unroll
        for (int ks = 0; ks < NKS; ++ks)
            qf[qq][ks] = *(const short8*)(qbase + (size_t)(q0 + qq*16 + n16)*DOUT + ks*32 + q4*8);

    f32x4 acc[NQ][NMT];
    #pragma unroll
    for (int qq = 0; qq < NQ; ++qq)
        #pragma unroll
        for (int mt = 0; mt < NMT; ++mt) acc[qq][mt] = f32x4{0.f, 0.f, 0.f, 0.f};
    float l_lane[NQ];
    #pragma unroll
    for (int qq = 0; qq < NQ; ++qq) l_lane[qq] = 0.f;

    // bpermute source lanes for the P gather (uniform per lane)
    const int srcA = n16 + ((q4 & 1) * 2) * 16;
    const int srcB = srcA + 16;
    const bool selhi = (q4 >= 2);

    for (int kt0 = 0; kt0 < ITERS; ++kt0) {
        const int kt = wave * ITERS + kt0;     // this wave's key chunk (64 keys)
        const short* krow = kbase + (size_t)(kt*64)*DOUT;
        const short* vrow = vbase + (size_t)kt*128*64;

        // Two halves: scores for m-tiles {2h, 2h+1} (32 keys) then PV ks2=h.
        // Keeps w0v/w1v liveness at 2 m-tiles -> lower register peak (MODE1 NQ=4).
        #pragma unroll
        for (int h = 0; h < 2; ++h) {
            unsigned w0v[NQ][2], w1v[NQ][2];
            #pragma unroll
            for (int m2 = 0; m2 < 2; ++m2) {
                const int mt = h*2 + m2;
                f32x4 c[NQ];
                #pragma unroll
                for (int qq = 0; qq < NQ; ++qq) c[qq] = f32x4{0.f, 0.f, 0.f, 0.f};
                #pragma unroll
                for (int ks = 0; ks < NKS; ++ks) {
                    short8 kf = *(const short8*)(krow + (size_t)(mt*16 + n16)*DOUT + ks*32 + q4*8);
                    #pragma unroll
                    for (int qq = 0; qq < NQ; ++qq)
                        c[qq] = __builtin_amdgcn_mfma_f32_16x16x32_bf16(kf, qf[qq][ks], c[qq], 0, 0, 0);
                }
                #pragma unroll
                for (int qq = 0; qq < NQ; ++qq) {
                    #pragma unroll
                    for (int r = 0; r < 4; ++r) {
                        float p = __expf(c[qq][r] * scale);
                        c[qq][r] = p;
                        l_lane[qq] += p;
                    }
                    w0v[qq][m2] = bfbits(c[qq][0]) | (bfbits(c[qq][1]) << 16);
                    w1v[qq][m2] = bfbits(c[qq][2]) | (bfbits(c[qq][3]) << 16);
                }
            }
            // ---- gather P fragments for this half, then PV (keys h*32..h*32+31)
            short8 pf[NQ];
            #pragma unroll
            for (int qq = 0; qq < NQ; ++qq) {
                int4v pw;
                { unsigned a = __shfl(w0v[qq][0], srcA), bx = __shfl(w0v[qq][1], srcA);
                  pw.x = selhi ? (int)bx : (int)a; }
                { unsigned a = __shfl(w1v[qq][0], srcA), bx = __shfl(w1v[qq][1], srcA);
                  pw.y = selhi ? (int)bx : (int)a; }
                { unsigned a = __shfl(w0v[qq][0], srcB), bx = __shfl(w0v[qq][1], srcB);
                  pw.z = selhi ? (int)bx : (int)a; }
                { unsigned a = __shfl(w1v[qq][0], srcB), bx = __shfl(w1v[qq][1], srcB);
                  pw.w = selhi ? (int)bx : (int)a; }
                pf[qq] = __builtin_bit_cast(short8, pw);
            }
            #pragma unroll
            for (int mt = 0; mt < NMT; ++mt) {
                short8 vf = *(const short8*)(vrow + (size_t)(mt*16 + n16)*64 + h*32 + q4*8);
                #pragma unroll
                for (int qq = 0; qq < NQ; ++qq)
                    acc[qq][mt] = __builtin_amdgcn_mfma_f32_16x16x32_bf16(vf, pf[qq], acc[qq][mt], 0, 0, 0);
            }
        }
    }

    // ---- finalize denominators: reduce across q4 groups
    #pragma unroll
    for (int qq = 0; qq < NQ; ++qq) {
        l_lane[qq] += __shfl_xor(l_lane[qq], 16);
        l_lane[qq] += __shfl_xor(l_lane[qq], 32);
        if (q4 == 0) lbuf[wave][qq*16 + n16] = l_lane[qq];
    }

    // ---- publish O^T partials
    if (MODE == 0) {
        float (&oSf)[NW][NQ*16][D + 1] = *reinterpret_cast<float (*)[NW][NQ*16][D + 1]>(oS_raw);
        #pragma unroll
        for (int qq = 0; qq < NQ; ++qq)
            #pragma unroll
            for (int mt = 0; mt < NMT; ++mt)
                #pragma unroll
                for (int r = 0; r < 4; ++r)
                    oSf[wave][qq*16 + n16][mt*16 + q4*4 + r] = acc[qq][mt][r];
    } else {
        unsigned short (&oSh)[NW][NQ*16][D + 2] =
            *reinterpret_cast<unsigned short (*)[NW][NQ*16][D + 2]>(oS_raw);
        #pragma unroll
        for (int qq = 0; qq < NQ; ++qq)
            #pragma unroll
            for (int mt = 0; mt < NMT; ++mt)
                #pragma unroll
                for (int r = 0; r < 4; ++r)
                    oSh[wave][qq*16 + n16][mt*16 + q4*4 + r] = (unsigned short)bfbits(acc[qq][mt][r]);
    }
    __syncthreads();  // single barrier: merge reads all splits

    if (MODE == 0) {
        // merge + ReLU per q-tile: lane handles query wave*4+(lane>>4), dims (lane&15)*2..+1
        float (&oSf)[NW][NQ*16][D + 1] = *reinterpret_cast<float (*)[NW][NQ*16][D + 1]>(oS_raw);
        const int ql = wave*4 + (lane >> 4);
        const int d2 = (lane & 15)*2;
        #pragma unroll
        for (int qq = 0; qq < NQ; ++qq) {
            const int row = qq*16 + ql;
            float denom = 0.f, o0 = 0.f, o1 = 0.f;
            #pragma unroll
            for (int s = 0; s < NW; ++s) {
                denom += lbuf[s][row];
                o0 += oSf[s][row][d2];
                o1 += oSf[s][row][d2 + 1];
            }
            float di = 1.f / denom;
            unsigned w = bfbits(fmaxf(o0*di, 0.f)) | (bfbits(fmaxf(o1*di, 0.f)) << 16);
            *(unsigned*)&hout[((size_t)b*NN + q0 + row)*DOUT + hd*32 + d2] = w;
        }
    } else {
        // merge + residual + LayerNorm per q-tile: lane handles query wave*2+(lane>>5),
        // dims (lane&31)*4..+3; row reduction via shfl_xor 16..1.
        unsigned short (&oSh)[NW][NQ*16][D + 2] =
            *reinterpret_cast<unsigned short (*)[NW][NQ*16][D + 2]>(oS_raw);
        const int ql = wave*2 + (lane >> 5);
        const int il = lane & 31;
        #pragma unroll
        for (int qq = 0; qq < NQ; ++qq) {
            const int row = qq*16 + ql;
            float denom = 0.f;
            #pragma unroll
            for (int s = 0; s < NW; ++s) denom += lbuf[s][row];
            float di = 1.f / denom;
            size_t base = ((size_t)b*NN + q0 + row)*DOUT + il*4;
            float4 pr = *(const float4*)(proj + base);
            float y[4];
            #pragma unroll
            for (int c = 0; c < 4; ++c) {
                float o = 0.f;
                #pragma unroll
                for (int s = 0; s < NW; ++s)
                    o += __uint_as_float(((unsigned)oSh[s][row][il*4 + c]) << 16);
                y[c] = o*di + ((const float*)&pr)[c];
            }
            float ssum = y[0] + y[1] + y[2] + y[3];
            #pragma unroll
            for (int off = 16; off >= 1; off >>= 1) ssum += __shfl_xor(ssum, off);
            float mu = ssum * (1.f/128.f);
            float vs = 0.f;
            #pragma unroll
            for (int c = 0; c < 4; ++c) { float d = y[c] - mu; vs += d*d; }
            #pragma unroll
            for (int off = 16; off >= 1; off >>= 1) vs += __shfl_xor(vs, off);
            float rs = rsqrtf(vs * (1.f/128.f) + 1e-3f);
            float4 g4 = *(const float4*)(lng + il*4);
            float4 b4 = *(const float4*)(lnb + il*4);
            float4 o4;
            #pragma unroll
            for (int c = 0; c < 4; ++c) {
                float o = (y[c] - mu)*rs*((const float*)&g4)[c] + ((const float*)&b4)[c];
                if (!(o == o)) o = 12345.0f;  // NaN sentinel (never hit on a passing run)
                ((float*)&o4)[c] = o;
            }
            *(float4*)(fout + base) = o4;
        }
    }
}

extern "C" void kernel_launch(void* const* d_in, const int* in_sizes, int n_in,
                              void* d_out, int out_size, void* d_ws, size_t ws_size,
                              hipStream_t stream)
{
    const float* x   = (const float*)d_in[0];
    // d_in[1] = emb is dead: adj = sigmoid(l2norm(emb)@l2norm(emb)^T) in [0.27,1],
    // diag forced 1 -> adj==0 never true -> dense attention.
    const float* q1w = (const float*)d_in[2];
    const float* q1b = (const float*)d_in[3];
    const float* k1w = (const float*)d_in[4];
    const float* k1b = (const float*)d_in[5];
    const float* v1w = (const float*)d_in[6];
    const float* v1b = (const float*)d_in[7];
    const float* q2w = (const float*)d_in[8];
    const float* q2b = (const float*)d_in[9];
    const float* k2w = (const float*)d_in[10];
    const float* k2b = (const float*)d_in[11];
    const float* v2w = (const float*)d_in[12];
    const float* v2b = (const float*)d_in[13];
    const float* pw  = (const float*)d_in[14];
    const float* lng = (const float*)d_in[15];
    const float* lnb = (const float*)d_in[16];

    // Workspace: 12 MB (proven). q/k/vT slots reused across the two layers.
    const size_t SZ = (size_t)NB*NN*DOUT;           // 1,048,576 elements
    char* wsb = (char*)d_ws;
    bf16*  qA   = (bf16*)(wsb + 0*SZ*2);            // 2 MB
    bf16*  kA   = (bf16*)(wsb + 1*SZ*2);            // 2 MB
    bf16*  vT   = (bf16*)(wsb + 2*SZ*2);            // 2 MB  [b][key/64][128][64]
    float* proj = (float*)(wsb + 3*SZ*2);           // 4 MB
    bf16*  h    = (bf16*)(wsb + 3*SZ*2 + SZ*4);     // 2 MB

    k_gemm1<<<dim3(128, 8), 256, 0, stream>>>(x, q1w, q1b, k1w, k1b, v1w, v1b, pw,
                                              qA, kA, vT, proj);
    // NQ=4, NW=4: 512 blocks (32 q-blocks x 16 bh), 256 threads
    k_attn_mfma<32, 0, 4, 4><<<dim3(32, 16), 256, 0, stream>>>(
        qA, kA, vT, nullptr, nullptr, nullptr, h, nullptr);
    k_gemm2<<<dim3(128, 6), 256, 0, stream>>>(h, q2w, q2b, k2w, k2b, v2w, v2b,
                                              qA, kA, vT);
    // NQ=4, NW=8: 128 blocks (32 q-blocks x 4 b), 512 threads
    k_attn_mfma<128, 1, 8, 4><<<dim3(32, 4), 512, 0, stream>>>(
        qA, kA, vT, proj, lng, lnb, nullptr, (float*)d_out);
}

// Round 7
// 195.453 us; speedup vs baseline: 1.0984x; 1.0984x over previous
//
#include <hip/hip_runtime.h>
#include <hip/hip_bf16.h>

#define NB 4
#define NN 2048
#define FIN 64
#define DOUT 128

typedef __hip_bfloat16 bf16;
typedef __attribute__((ext_vector_type(8))) short short8;
typedef __attribute__((ext_vector_type(4))) float f32x4;
typedef __attribute__((ext_vector_type(4))) int int4v;

static __device__ __forceinline__ float bf2f(bf16 v) { return __bfloat162float(v); }
static __device__ __forceinline__ bf16  f2bf(float v) { return __float2bfloat16(v); }
static __device__ __forceinline__ unsigned bfbits(float v) {
    bf16 h = __float2bfloat16(v);
    return (unsigned)*reinterpret_cast<unsigned short*>(&h);
}

// vT layout (R2, kept): [b][key/64][dim 0..127][key%64] (bf16), dense 128B rows.
#define VT_IDX(b, key, d) ((((size_t)(b)*32 + ((key) >> 6))*128 + (d))*64 + ((key) & 63))

// ---------------- Kernel 1: q1,k1 (bf16), vT (bf16), proj (fp32) ----------------
__global__ __launch_bounds__(256) void k_gemm1(
    const float* __restrict__ x,
    const float* __restrict__ q1w, const float* __restrict__ q1b,
    const float* __restrict__ k1w, const float* __restrict__ k1b,
    const float* __restrict__ v1w, const float* __restrict__ v1b,
    const float* __restrict__ pw,
    bf16* __restrict__ qA, bf16* __restrict__ kA, bf16* __restrict__ vT,
    float* __restrict__ proj)
{
    __shared__ float At[64][65];
    __shared__ float Wt[64][65];
    const int rb = blockIdx.x;
    const int cb = blockIdx.y;
    const int mat = cb >> 1;
    const int c0 = (cb & 1) * 64;
    const float* W    = (mat==0)? q1w : (mat==1)? k1w : (mat==2)? v1w : pw;
    const float* bias = (mat==0)? q1b : (mat==1)? k1b : (mat==2)? v1b : nullptr;
    const int t = threadIdx.x;
    const int row0 = rb * 64;
    for (int e = t; e < 64*64; e += 256) {
        int r = e >> 6, c = e & 63;
        At[r][c] = x[(size_t)(row0 + r)*FIN + c];
        Wt[r][c] = W[r*DOUT + c0 + c];
    }
    __syncthreads();
    const int ty = t >> 4, tx = t & 15;
    float acc[4][4] = {};
    #pragma unroll 8
    for (int k = 0; k < 64; ++k) {
        float av[4], bv[4];
        #pragma unroll
        for (int i = 0; i < 4; ++i) av[i] = At[ty*4+i][k];
        #pragma unroll
        for (int j = 0; j < 4; ++j) bv[j] = Wt[k][tx*4+j];
        #pragma unroll
        for (int i = 0; i < 4; ++i)
            #pragma unroll
            for (int j = 0; j < 4; ++j)
                acc[i][j] = fmaf(av[i], bv[j], acc[i][j]);
    }
    #pragma unroll
    for (int i = 0; i < 4; ++i) {
        int gr = row0 + ty*4 + i;
        #pragma unroll
        for (int j = 0; j < 4; ++j) {
            int gc = c0 + tx*4 + j;
            float v = acc[i][j] + (bias ? bias[gc] : 0.f);
            if (mat == 0)      qA[(size_t)gr*DOUT + gc] = f2bf(v);
            else if (mat == 1) kA[(size_t)gr*DOUT + gc] = f2bf(v);
            else if (mat == 2) {
                int b = gr >> 11, n = gr & 2047;
                vT[VT_IDX(b, n, gc)] = f2bf(v);
            } else proj[(size_t)gr*DOUT + gc] = v;
        }
    }
}

// ---------------- Kernel 3: q2,k2 (bf16), vT = h @ W (+bias) ----------------
__global__ __launch_bounds__(256) void k_gemm2(
    const bf16* __restrict__ h,
    const float* __restrict__ q2w, const float* __restrict__ q2b,
    const float* __restrict__ k2w, const float* __restrict__ k2b,
    const float* __restrict__ v2w, const float* __restrict__ v2b,
    bf16* __restrict__ qA, bf16* __restrict__ kA, bf16* __restrict__ vT)
{
    __shared__ float At[64][65];
    __shared__ float Wt[64][65];
    const int rb = blockIdx.x, cb = blockIdx.y;
    const int mat = cb >> 1, c0 = (cb & 1)*64;
    const float* W    = (mat==0)? q2w : (mat==1)? k2w : v2w;
    const float* bias = (mat==0)? q2b : (mat==1)? k2b : v2b;
    const int t = threadIdx.x, ty = t >> 4, tx = t & 15, row0 = rb*64;
    float acc[4][4] = {};
    for (int kc = 0; kc < 2; ++kc) {
        __syncthreads();
        for (int e = t; e < 64*64; e += 256) {
            int r = e >> 6, c = e & 63;
            At[r][c] = bf2f(h[(size_t)(row0+r)*DOUT + kc*64 + c]);
            Wt[r][c] = W[(kc*64+r)*DOUT + c0 + c];
        }
        __syncthreads();
        #pragma unroll 8
        for (int k = 0; k < 64; ++k) {
            float av[4], bv[4];
            #pragma unroll
            for (int i = 0; i < 4; ++i) av[i] = At[ty*4+i][k];
            #pragma unroll
            for (int j = 0; j < 4; ++j) bv[j] = Wt[k][tx*4+j];
            #pragma unroll
            for (int i = 0; i < 4; ++i)
                #pragma unroll
                for (int j = 0; j < 4; ++j)
                    acc[i][j] = fmaf(av[i], bv[j], acc[i][j]);
        }
    }
    #pragma unroll
    for (int i = 0; i < 4; ++i) {
        int gr = row0 + ty*4 + i;
        #pragma unroll
        for (int j = 0; j < 4; ++j) {
            int gc = c0 + tx*4 + j;
            float v = acc[i][j] + bias[gc];
            if (mat == 0)      qA[(size_t)gr*DOUT + gc] = f2bf(v);
            else if (mat == 1) kA[(size_t)gr*DOUT + gc] = f2bf(v);
            else {
                int b = gr >> 11, n = gr & 2047;
                vT[VT_IDX(b, n, gc)] = f2bf(v);
            }
        }
    }
}

// ---------------- MFMA flash attention v7 ----------------
// r6 lessons: (1) NQ=4 MODE1 blew LDS (132KB -> 1 blk/CU, half-chip grid) and
// spilled (VGPR 128 cap is a hard compiler behavior on 512-thr blocks, WRITE 25.6MB).
// (2) MODE0 traffic halving at constant occupancy was FLAT -> below ~256MB the
// kernels are latency/occupancy-bound, not request-bound. Lever = TLP.
// R7: MODE1 reverted to exact r5 (NQ=2,NW=8,256 blks, ~40us proven). MODE0 ->
// NQ=4 + NW=8: same traffic as r6 but 512 blks x 8 waves = 16 waves/CU (2x r6),
// LDS 68KB (2 blk/CU). Single-variable tests both directions.
// MODE 0: relu -> h bf16 (gat1, D=32, H=4). MODE 1: +proj residual + LayerNorm -> fp32.
template<int D, int MODE, int NW, int NQ>
__global__ __launch_bounds__(NW*64, 2) void k_attn_mfma(
    const bf16* __restrict__ qA, const bf16* __restrict__ kA, const bf16* __restrict__ vT,
    const float* __restrict__ proj, const float* __restrict__ lng, const float* __restrict__ lnb,
    bf16* __restrict__ hout, float* __restrict__ fout)
{
    constexpr int NKS = D / 32;     // 32-dim k-steps in S^T
    constexpr int NMT = D / 16;     // 16-dim m-tiles of O^T
    constexpr int ITERS = NN / (64 * NW);

    __shared__ float lbuf[NW][NQ*16];
    constexpr int OSW = (MODE == 0) ? (D + 1) : (D + 2);
    __shared__ char oS_raw[(size_t)NW * NQ*16 * OSW * ((MODE == 0) ? 4 : 2)];

    const float scale = (D == 32) ? 0.17677669529663687f : 0.08838834764831843f;

    // XCD-aware swizzle (xcd = linear_wg % 8).
    const unsigned wg  = blockIdx.x + (unsigned)gridDim.x * blockIdx.y;
    const unsigned xcd = wg & 7u;
    const unsigned idx = wg >> 3;
    int qb, bh;
    if constexpr (MODE == 0) {
        // 512 wgs: idx 0..63. 2 adjacent heads per XCD; 32 q-blocks.
        bh = (int)((xcd << 1) | (idx >> 5));   // 0..15
        qb = (int)(idx & 31u);                 // 0..31
    } else {
        // 256 wgs: idx 0..31. 1 batch per XCD-pair; 64 q-blocks.
        bh = (int)(xcd >> 1);                  // 0..3
        qb = (int)(((xcd & 1u) << 5) | idx);   // 0..63
    }

    const int b  = (MODE == 0) ? (bh >> 2) : bh;
    const int hd = (MODE == 0) ? (bh & 3) : 0;
    const int q0 = qb * (16*NQ);
    const int wave = threadIdx.x >> 6, lane = threadIdx.x & 63;
    const int n16 = lane & 15, q4 = lane >> 4;

    const short* qbase = (const short*)qA + ((size_t)b*NN)*DOUT + hd*32;
    const short* kbase = (const short*)kA + ((size_t)b*NN)*DOUT + hd*32;
    const short* vbase = (const short*)vT + (size_t)b*32*128*64 + (size_t)(hd*32)*64;

    // Q B-fragments for each of the NQ query tiles — held in regs
    short8 qf[NQ][NKS];
    #pragma unroll
    for (int qq = 0; qq < NQ; ++qq)
        #pragma unroll
        for (int ks = 0; ks < NKS; ++ks)
            qf[qq][ks] = *(const short8*)(qbase + (size_t)(q0 + qq*16 + n16)*DOUT + ks*32 + q4*8);

    f32x4 acc[NQ][NMT];
    #pragma unroll
    for (int qq = 0; qq < NQ; ++qq)
        #pragma unroll
        for (int mt = 0; mt < NMT; ++mt) acc[qq][mt] = f32x4{0.f, 0.f, 0.f, 0.f};
    float l_lane[NQ];
    #pragma unroll
    for (int qq = 0; qq < NQ; ++qq) l_lane[qq] = 0.f;

    // bpermute source lanes for the P gather (uniform per lane)
    const int srcA = n16 + ((q4 & 1) * 2) * 16;
    const int srcB = srcA + 16;
    const bool selhi = (q4 >= 2);

    for (int kt0 = 0; kt0 < ITERS; ++kt0) {
        const int kt = wave * ITERS + kt0;     // this wave's key chunk (64 keys)
        const short* krow = kbase + (size_t)(kt*64)*DOUT;
        const short* vrow = vbase + (size_t)kt*128*64;

        // ---- S^T: 4 m-tiles of 16 keys; each K fragment feeds NQ MFMAs.
        unsigned w0v[NQ][4], w1v[NQ][4];
        #pragma unroll
        for (int mt = 0; mt < 4; ++mt) {
            f32x4 c[NQ];
            #pragma unroll
            for (int qq = 0; qq < NQ; ++qq) c[qq] = f32x4{0.f, 0.f, 0.f, 0.f};
            #pragma unroll
            for (int ks = 0; ks < NKS; ++ks) {
                short8 kf = *(const short8*)(krow + (size_t)(mt*16 + n16)*DOUT + ks*32 + q4*8);
                #pragma unroll
                for (int qq = 0; qq < NQ; ++qq)
                    c[qq] = __builtin_amdgcn_mfma_f32_16x16x32_bf16(kf, qf[qq][ks], c[qq], 0, 0, 0);
            }
            // exp (no-max), accumulate denominator, pack immediately (short live range)
            #pragma unroll
            for (int qq = 0; qq < NQ; ++qq) {
                #pragma unroll
                for (int r = 0; r < 4; ++r) {
                    float p = __expf(c[qq][r] * scale);
                    c[qq][r] = p;
                    l_lane[qq] += p;
                }
                w0v[qq][mt] = bfbits(c[qq][0]) | (bfbits(c[qq][1]) << 16);
                w1v[qq][mt] = bfbits(c[qq][2]) | (bfbits(c[qq][3]) << 16);
            }
        }

        // ---- PV: 2 k-steps of 32 keys; each V fragment feeds NQ MFMAs.
        #pragma unroll
        for (int ks2 = 0; ks2 < 2; ++ks2) {
            const int t0 = ks2*2, t1 = ks2*2 + 1;
            short8 pf[NQ];
            #pragma unroll
            for (int qq = 0; qq < NQ; ++qq) {
                int4v pw;
                { unsigned a = __shfl(w0v[qq][t0], srcA), bx = __shfl(w0v[qq][t1], srcA);
                  pw.x = selhi ? (int)bx : (int)a; }
                { unsigned a = __shfl(w1v[qq][t0], srcA), bx = __shfl(w1v[qq][t1], srcA);
                  pw.y = selhi ? (int)bx : (int)a; }
                { unsigned a = __shfl(w0v[qq][t0], srcB), bx = __shfl(w0v[qq][t1], srcB);
                  pw.z = selhi ? (int)bx : (int)a; }
                { unsigned a = __shfl(w1v[qq][t0], srcB), bx = __shfl(w1v[qq][t1], srcB);
                  pw.w = selhi ? (int)bx : (int)a; }
                pf[qq] = __builtin_bit_cast(short8, pw);
            }
            #pragma unroll
            for (int mt = 0; mt < NMT; ++mt) {
                short8 vf = *(const short8*)(vrow + (size_t)(mt*16 + n16)*64 + ks2*32 + q4*8);
                #pragma unroll
                for (int qq = 0; qq < NQ; ++qq)
                    acc[qq][mt] = __builtin_amdgcn_mfma_f32_16x16x32_bf16(vf, pf[qq], acc[qq][mt], 0, 0, 0);
            }
        }
    }

    // ---- finalize denominators: reduce across q4 groups
    #pragma unroll
    for (int qq = 0; qq < NQ; ++qq) {
        l_lane[qq] += __shfl_xor(l_lane[qq], 16);
        l_lane[qq] += __shfl_xor(l_lane[qq], 32);
        if (q4 == 0) lbuf[wave][qq*16 + n16] = l_lane[qq];
    }

    // ---- publish O^T partials
    if (MODE == 0) {
        float (&oSf)[NW][NQ*16][D + 1] = *reinterpret_cast<float (*)[NW][NQ*16][D + 1]>(oS_raw);
        #pragma unroll
        for (int qq = 0; qq < NQ; ++qq)
            #pragma unroll
            for (int mt = 0; mt < NMT; ++mt)
                #pragma unroll
                for (int r = 0; r < 4; ++r)
                    oSf[wave][qq*16 + n16][mt*16 + q4*4 + r] = acc[qq][mt][r];
    } else {
        unsigned short (&oSh)[NW][NQ*16][D + 2] =
            *reinterpret_cast<unsigned short (*)[NW][NQ*16][D + 2]>(oS_raw);
        #pragma unroll
        for (int qq = 0; qq < NQ; ++qq)
            #pragma unroll
            for (int mt = 0; mt < NMT; ++mt)
                #pragma unroll
                for (int r = 0; r < 4; ++r)
                    oSh[wave][qq*16 + n16][mt*16 + q4*4 + r] = (unsigned short)bfbits(acc[qq][mt][r]);
    }
    __syncthreads();  // single barrier: merge reads all splits

    if (MODE == 0) {
        // merge + ReLU per q-tile. Waves 0-3 merge (NW may be 8: waves 4-7 only
        // published partials; epilogue is tiny). lane -> query (wave&3)*4+(lane>>4),
        // dims (lane&15)*2..+1
        float (&oSf)[NW][NQ*16][D + 1] = *reinterpret_cast<float (*)[NW][NQ*16][D + 1]>(oS_raw);
        if (wave < 4) {
            const int ql = (wave & 3)*4 + (lane >> 4);
            const int d2 = (lane & 15)*2;
            #pragma unroll
            for (int qq = 0; qq < NQ; ++qq) {
                const int row = qq*16 + ql;
                float denom = 0.f, o0 = 0.f, o1 = 0.f;
                #pragma unroll
                for (int s = 0; s < NW; ++s) {
                    denom += lbuf[s][row];
                    o0 += oSf[s][row][d2];
                    o1 += oSf[s][row][d2 + 1];
                }
                float di = 1.f / denom;
                unsigned w = bfbits(fmaxf(o0*di, 0.f)) | (bfbits(fmaxf(o1*di, 0.f)) << 16);
                *(unsigned*)&hout[((size_t)b*NN + q0 + row)*DOUT + hd*32 + d2] = w;
            }
        }
    } else {
        // merge + residual + LayerNorm per q-tile: lane handles query wave*2+(lane>>5),
        // dims (lane&31)*4..+3; row reduction via shfl_xor 16..1.
        unsigned short (&oSh)[NW][NQ*16][D + 2] =
            *reinterpret_cast<unsigned short (*)[NW][NQ*16][D + 2]>(oS_raw);
        const int ql = wave*2 + (lane >> 5);
        const int il = lane & 31;
        #pragma unroll
        for (int qq = 0; qq < NQ; ++qq) {
            const int row = qq*16 + ql;
            float denom = 0.f;
            #pragma unroll
            for (int s = 0; s < NW; ++s) denom += lbuf[s][row];
            float di = 1.f / denom;
            size_t base = ((size_t)b*NN + q0 + row)*DOUT + il*4;
            float4 pr = *(const float4*)(proj + base);
            float y[4];
            #pragma unroll
            for (int c = 0; c < 4; ++c) {
                float o = 0.f;
                #pragma unroll
                for (int s = 0; s < NW; ++s)
                    o += __uint_as_float(((unsigned)oSh[s][row][il*4 + c]) << 16);
                y[c] = o*di + ((const float*)&pr)[c];
            }
            float ssum = y[0] + y[1] + y[2] + y[3];
            #pragma unroll
            for (int off = 16; off >= 1; off >>= 1) ssum += __shfl_xor(ssum, off);
            float mu = ssum * (1.f/128.f);
            float vs = 0.f;
            #pragma unroll
            for (int c = 0; c < 4; ++c) { float d = y[c] - mu; vs += d*d; }
            #pragma unroll
            for (int off = 16; off >= 1; off >>= 1) vs += __shfl_xor(vs, off);
            float rs = rsqrtf(vs * (1.f/128.f) + 1e-3f);
            float4 g4 = *(const float4*)(lng + il*4);
            float4 b4 = *(const float4*)(lnb + il*4);
            float4 o4;
            #pragma unroll
            for (int c = 0; c < 4; ++c) {
                float o = (y[c] - mu)*rs*((const float*)&g4)[c] + ((const float*)&b4)[c];
                if (!(o == o)) o = 12345.0f;  // NaN sentinel (never hit on a passing run)
                ((float*)&o4)[c] = o;
            }
            *(float4*)(fout + base) = o4;
        }
    }
}

extern "C" void kernel_launch(void* const* d_in, const int* in_sizes, int n_in,
                              void* d_out, int out_size, void* d_ws, size_t ws_size,
                              hipStream_t stream)
{
    const float* x   = (const float*)d_in[0];
    // d_in[1] = emb is dead: adj = sigmoid(l2norm(emb)@l2norm(emb)^T) in [0.27,1],
    // diag forced 1 -> adj==0 never true -> dense attention.
    const float* q1w = (const float*)d_in[2];
    const float* q1b = (const float*)d_in[3];
    const float* k1w = (const float*)d_in[4];
    const float* k1b = (const float*)d_in[5];
    const float* v1w = (const float*)d_in[6];
    const float* v1b = (const float*)d_in[7];
    const float* q2w = (const float*)d_in[8];
    const float* q2b = (const float*)d_in[9];
    const float* k2w = (const float*)d_in[10];
    const float* k2b = (const float*)d_in[11];
    const float* v2w = (const float*)d_in[12];
    const float* v2b = (const float*)d_in[13];
    const float* pw  = (const float*)d_in[14];
    const float* lng = (const float*)d_in[15];
    const float* lnb = (const float*)d_in[16];

    // Workspace: 12 MB (proven). q/k/vT slots reused across the two layers.
    const size_t SZ = (size_t)NB*NN*DOUT;           // 1,048,576 elements
    char* wsb = (char*)d_ws;
    bf16*  qA   = (bf16*)(wsb + 0*SZ*2);            // 2 MB
    bf16*  kA   = (bf16*)(wsb + 1*SZ*2);            // 2 MB
    bf16*  vT   = (bf16*)(wsb + 2*SZ*2);            // 2 MB  [b][key/64][128][64]
    float* proj = (float*)(wsb + 3*SZ*2);           // 4 MB
    bf16*  h    = (bf16*)(wsb + 3*SZ*2 + SZ*4);     // 2 MB

    k_gemm1<<<dim3(128, 8), 256, 0, stream>>>(x, q1w, q1b, k1w, k1b, v1w, v1b, pw,
                                              qA, kA, vT, proj);
    // MODE0: NQ=4, NW=8 -> 512 blocks (32 q-blocks x 16 bh), 512 threads,
    // 16 waves/CU, LDS ~68KB (2 blocks/CU)
    k_attn_mfma<32, 0, 8, 4><<<dim3(32, 16), 512, 0, stream>>>(
        qA, kA, vT, nullptr, nullptr, nullptr, h, nullptr);
    k_gemm2<<<dim3(128, 6), 256, 0, stream>>>(h, q2w, q2b, k2w, k2b, v2w, v2b,
                                              qA, kA, vT);
    // MODE1: exact r5 revert — NQ=2, NW=8 -> 256 blocks (64 q-blocks x 4 b), 512 threads
    k_attn_mfma<128, 1, 8, 2><<<dim3(64, 4), 512, 0, stream>>>(
        qA, kA, vT, proj, lng, lnb, nullptr, (float*)d_out);
}

// Round 8
// 190.250 us; speedup vs baseline: 1.1285x; 1.0273x over previous
//
#include <hip/hip_runtime.h>
#include <hip/hip_bf16.h>

#define NB 4
#define NN 2048
#define FIN 64
#define DOUT 128

typedef __hip_bfloat16 bf16;
typedef __attribute__((ext_vector_type(8))) short short8;
typedef __attribute__((ext_vector_type(4))) float f32x4;
typedef __attribute__((ext_vector_type(4))) int int4v;

static __device__ __forceinline__ float bf2f(bf16 v) { return __bfloat162float(v); }
static __device__ __forceinline__ bf16  f2bf(float v) { return __float2bfloat16(v); }
static __device__ __forceinline__ unsigned bfbits(float v) {
    bf16 h = __float2bfloat16(v);
    return (unsigned)*reinterpret_cast<unsigned short*>(&h);
}

// ---------------- R8: fragment-linear operand layouts ----------------
// Every attn MFMA fragment load becomes base + frag*512shorts + lane*8shorts =
// contiguous 1KB per wave (4 cache lines) instead of 16 scattered 64B lines.
// Layer1 (H=4, D=32, NKS=1, NMT=2):
//   qA/kA: [(b*4+hd)][t16 0..127][lane][8]            (65536 shorts per (b,hd))
//   vT:    [(b*4+hd)][kt 0..31][mt 0..1][ks2 0..1][lane][8]
// Layer2 (H=1, D=128, NKS=4, NMT=8):
//   qA/kA: [b][t16 0..127][ks 0..3][lane][8]
//   vT:    [b][kt 0..31][mt 0..7][ks2 0..1][lane][8]
// Producers (gemm1/gemm2) compute the inverse index per output element.

// ---------------- Kernel 1: q1,k1,vT (bf16 fragment-linear), proj (fp32) ----------------
__global__ __launch_bounds__(256) void k_gemm1(
    const float* __restrict__ x,
    const float* __restrict__ q1w, const float* __restrict__ q1b,
    const float* __restrict__ k1w, const float* __restrict__ k1b,
    const float* __restrict__ v1w, const float* __restrict__ v1b,
    const float* __restrict__ pw,
    bf16* __restrict__ qA, bf16* __restrict__ kA, bf16* __restrict__ vT,
    float* __restrict__ proj)
{
    __shared__ float At[64][65];
    __shared__ float Wt[64][65];
    const int rb = blockIdx.x;
    const int cb = blockIdx.y;
    const int mat = cb >> 1;
    const int c0 = (cb & 1) * 64;
    const float* W    = (mat==0)? q1w : (mat==1)? k1w : (mat==2)? v1w : pw;
    const float* bias = (mat==0)? q1b : (mat==1)? k1b : (mat==2)? v1b : nullptr;
    const int t = threadIdx.x;
    const int row0 = rb * 64;
    // vectorized staging: 1024 float4 per tile
    for (int e = t; e < 1024; e += 256) {
        int r = e >> 4, c4 = e & 15;
        *(float4*)&At[r][c4*4] = *(const float4*)&x[(size_t)(row0 + r)*FIN + c4*4];
        *(float4*)&Wt[r][c4*4] = *(const float4*)&W[(size_t)r*DOUT + c0 + c4*4];
    }
    __syncthreads();
    const int ty = t >> 4, tx = t & 15;
    float acc[4][4] = {};
    #pragma unroll 8
    for (int k = 0; k < 64; ++k) {
        float av[4], bv[4];
        #pragma unroll
        for (int i = 0; i < 4; ++i) av[i] = At[ty*4+i][k];
        #pragma unroll
        for (int j = 0; j < 4; ++j) bv[j] = Wt[k][tx*4+j];
        #pragma unroll
        for (int i = 0; i < 4; ++i)
            #pragma unroll
            for (int j = 0; j < 4; ++j)
                acc[i][j] = fmaf(av[i], bv[j], acc[i][j]);
    }
    #pragma unroll
    for (int i = 0; i < 4; ++i) {
        int gr = row0 + ty*4 + i;
        int b = gr >> 11, n = gr & 2047;
        #pragma unroll
        for (int j = 0; j < 4; ++j) {
            int gc = c0 + tx*4 + j;
            float v = acc[i][j] + (bias ? bias[gc] : 0.f);
            if (mat == 3) { proj[(size_t)gr*DOUT + gc] = v; continue; }
            int hd = gc >> 5, d32 = gc & 31;
            if (mat == 2) {
                // v fragment-linear (layer1)
                int kt = n >> 6, ks2 = (n >> 5) & 1, q4k = (n >> 3) & 3, jk = n & 7;
                int mt = d32 >> 4, n16d = d32 & 15;
                size_t idx = ((((size_t)(b*4+hd)*32 + kt)*2 + mt)*2 + ks2)*512
                             + (size_t)(q4k*16 + n16d)*8 + jk;
                vT[idx] = f2bf(v);
            } else {
                // q/k fragment-linear (layer1)
                size_t idx = ((size_t)(b*4+hd)*128 + (n >> 4))*512
                             + (size_t)((d32 >> 3)*16 + (n & 15))*8 + (d32 & 7);
                if (mat == 0) qA[idx] = f2bf(v); else kA[idx] = f2bf(v);
            }
        }
    }
}

// ---------------- Kernel 3: q2,k2,vT (fragment-linear layer2) = h @ W (+bias) ----------------
__global__ __launch_bounds__(256) void k_gemm2(
    const bf16* __restrict__ h,
    const float* __restrict__ q2w, const float* __restrict__ q2b,
    const float* __restrict__ k2w, const float* __restrict__ k2b,
    const float* __restrict__ v2w, const float* __restrict__ v2b,
    bf16* __restrict__ qA, bf16* __restrict__ kA, bf16* __restrict__ vT)
{
    __shared__ float At[64][65];
    __shared__ float Wt[64][65];
    const int rb = blockIdx.x, cb = blockIdx.y;
    const int mat = cb >> 1, c0 = (cb & 1)*64;
    const float* W    = (mat==0)? q2w : (mat==1)? k2w : v2w;
    const float* bias = (mat==0)? q2b : (mat==1)? k2b : v2b;
    const int t = threadIdx.x, ty = t >> 4, tx = t & 15, row0 = rb*64;
    float acc[4][4] = {};
    for (int kc = 0; kc < 2; ++kc) {
        __syncthreads();
        // h: vectorized short8 loads (512 per tile); W: float4 (1024 per tile)
        for (int e = t; e < 512; e += 256) {
            int r = e >> 3, c8 = e & 7;
            short8 hv = *(const short8*)&h[(size_t)(row0+r)*DOUT + kc*64 + c8*8];
            #pragma unroll
            for (int u = 0; u < 8; ++u)
                At[r][c8*8 + u] = __uint_as_float(((unsigned)(unsigned short)hv[u]) << 16);
        }
        for (int e = t; e < 1024; e += 256) {
            int r = e >> 4, c4 = e & 15;
            *(float4*)&Wt[r][c4*4] = *(const float4*)&W[(size_t)(kc*64+r)*DOUT + c0 + c4*4];
        }
        __syncthreads();
        #pragma unroll 8
        for (int k = 0; k < 64; ++k) {
            float av[4], bv[4];
            #pragma unroll
            for (int i = 0; i < 4; ++i) av[i] = At[ty*4+i][k];
            #pragma unroll
            for (int j = 0; j < 4; ++j) bv[j] = Wt[k][tx*4+j];
            #pragma unroll
            for (int i = 0; i < 4; ++i)
                #pragma unroll
                for (int j = 0; j < 4; ++j)
                    acc[i][j] = fmaf(av[i], bv[j], acc[i][j]);
        }
    }
    #pragma unroll
    for (int i = 0; i < 4; ++i) {
        int gr = row0 + ty*4 + i;
        int b = gr >> 11, n = gr & 2047;
        #pragma unroll
        for (int j = 0; j < 4; ++j) {
            int gc = c0 + tx*4 + j;
            float v = acc[i][j] + bias[gc];
            if (mat == 2) {
                // v fragment-linear (layer2): NMT=8
                int kt = n >> 6, ks2 = (n >> 5) & 1, q4k = (n >> 3) & 3, jk = n & 7;
                int mt = gc >> 4, n16d = gc & 15;
                size_t idx = (((size_t)b*32 + kt)*8 + mt)*1024 + (size_t)ks2*512
                             + (size_t)(q4k*16 + n16d)*8 + jk;
                vT[idx] = f2bf(v);
            } else {
                // q/k fragment-linear (layer2): NKS=4
                int ks = gc >> 5, q4 = (gc >> 3) & 3, jj = gc & 7;
                size_t idx = ((size_t)b*128 + (n >> 4))*2048 + (size_t)ks*512
                             + (size_t)(q4*16 + (n & 15))*8 + jj;
                if (mat == 0) qA[idx] = f2bf(v); else kA[idx] = f2bf(v);
            }
        }
    }
}

// ---------------- MFMA flash attention v8: fragment-linear dense loads ----------------
// r7 finding: attn delivers ~6.4 TB/s = the dense-copy ceiling, but per-CU only
// ~50 GB/s vs 144 dense (m56): every fragment load touched 16 cache lines
// (row-strided). R8: operands pre-packed fragment-linear by the gemms; every
// global load here is base + frag*1KB + lane*16B -> contiguous 1KB, 4 lines.
// MODE 0: relu -> h bf16 (gat1, D=32, H=4). MODE 1: +proj residual + LayerNorm -> fp32.
template<int D, int MODE, int NW, int NQ>
__global__ __launch_bounds__(NW*64, 2) void k_attn_mfma(
    const bf16* __restrict__ qA, const bf16* __restrict__ kA, const bf16* __restrict__ vT,
    const float* __restrict__ proj, const float* __restrict__ lng, const float* __restrict__ lnb,
    bf16* __restrict__ hout, float* __restrict__ fout)
{
    constexpr int NKS = D / 32;     // 32-dim k-steps in S^T
    constexpr int NMT = D / 16;     // 16-dim m-tiles of O^T
    constexpr int ITERS = NN / (64 * NW);

    __shared__ float lbuf[NW][NQ*16];
    constexpr int OSW = (MODE == 0) ? (D + 1) : (D + 2);
    __shared__ char oS_raw[(size_t)NW * NQ*16 * OSW * ((MODE == 0) ? 4 : 2)];

    const float scale = (D == 32) ? 0.17677669529663687f : 0.08838834764831843f;

    // XCD-aware swizzle (xcd = linear_wg % 8).
    const unsigned wg  = blockIdx.x + (unsigned)gridDim.x * blockIdx.y;
    const unsigned xcd = wg & 7u;
    const unsigned idx = wg >> 3;
    int qb, bh;
    if constexpr (MODE == 0) {
        // 512 wgs: idx 0..63. 2 adjacent heads per XCD; 32 q-blocks.
        bh = (int)((xcd << 1) | (idx >> 5));   // 0..15
        qb = (int)(idx & 31u);                 // 0..31
    } else {
        // 256 wgs: idx 0..31. 1 batch per XCD-pair; 64 q-blocks.
        bh = (int)(xcd >> 1);                  // 0..3
        qb = (int)(((xcd & 1u) << 5) | idx);   // 0..63
    }

    const int b  = (MODE == 0) ? (bh >> 2) : bh;
    const int hd = (MODE == 0) ? (bh & 3) : 0;
    const int q0 = qb * (16*NQ);
    const int wave = threadIdx.x >> 6, lane = threadIdx.x & 63;
    const int n16 = lane & 15, q4 = lane >> 4;
    const int lane8 = lane * 8;

    // fragment-linear bases
    const short* qbase, * kbase, * vbase;
    if constexpr (MODE == 0) {
        qbase = (const short*)qA + (size_t)(b*4 + hd)*128*512;
        kbase = (const short*)kA + (size_t)(b*4 + hd)*128*512;
        vbase = (const short*)vT + (size_t)(b*4 + hd)*(32*NMT*2*512);
    } else {
        qbase = (const short*)qA + (size_t)b*128*NKS*512;
        kbase = (const short*)kA + (size_t)b*128*NKS*512;
        vbase = (const short*)vT + (size_t)b*(32*NMT*2*512);
    }

    // Q B-fragments for each of the NQ query tiles — held in regs
    short8 qf[NQ][NKS];
    #pragma unroll
    for (int qq = 0; qq < NQ; ++qq)
        #pragma unroll
        for (int ks = 0; ks < NKS; ++ks)
            qf[qq][ks] = *(const short8*)(qbase + ((size_t)(qb*NQ + qq)*NKS + ks)*512 + lane8);

    f32x4 acc[NQ][NMT];
    #pragma unroll
    for (int qq = 0; qq < NQ; ++qq)
        #pragma unroll
        for (int mt = 0; mt < NMT; ++mt) acc[qq][mt] = f32x4{0.f, 0.f, 0.f, 0.f};
    float l_lane[NQ];
    #pragma unroll
    for (int qq = 0; qq < NQ; ++qq) l_lane[qq] = 0.f;

    // bpermute source lanes for the P gather (uniform per lane)
    const int srcA = n16 + ((q4 & 1) * 2) * 16;
    const int srcB = srcA + 16;
    const bool selhi = (q4 >= 2);

    for (int kt0 = 0; kt0 < ITERS; ++kt0) {
        const int kt = wave * ITERS + kt0;     // this wave's key chunk (64 keys)

        // ---- S^T: 4 m-tiles of 16 keys; each K fragment feeds NQ MFMAs.
        unsigned w0v[NQ][4], w1v[NQ][4];
        #pragma unroll
        for (int mt = 0; mt < 4; ++mt) {
            f32x4 c[NQ];
            #pragma unroll
            for (int qq = 0; qq < NQ; ++qq) c[qq] = f32x4{0.f, 0.f, 0.f, 0.f};
            #pragma unroll
            for (int ks = 0; ks < NKS; ++ks) {
                short8 kf = *(const short8*)(kbase + ((size_t)(kt*4 + mt)*NKS + ks)*512 + lane8);
                #pragma unroll
                for (int qq = 0; qq < NQ; ++qq)
                    c[qq] = __builtin_amdgcn_mfma_f32_16x16x32_bf16(kf, qf[qq][ks], c[qq], 0, 0, 0);
            }
            // exp (no-max), accumulate denominator, pack immediately (short live range)
            #pragma unroll
            for (int qq = 0; qq < NQ; ++qq) {
                #pragma unroll
                for (int r = 0; r < 4; ++r) {
                    float p = __expf(c[qq][r] * scale);
                    c[qq][r] = p;
                    l_lane[qq] += p;
                }
                w0v[qq][mt] = bfbits(c[qq][0]) | (bfbits(c[qq][1]) << 16);
                w1v[qq][mt] = bfbits(c[qq][2]) | (bfbits(c[qq][3]) << 16);
            }
        }

        // ---- PV: 2 k-steps of 32 keys; each V fragment feeds NQ MFMAs.
        #pragma unroll
        for (int ks2 = 0; ks2 < 2; ++ks2) {
            const int t0 = ks2*2, t1 = ks2*2 + 1;
            short8 pf[NQ];
            #pragma unroll
            for (int qq = 0; qq < NQ; ++qq) {
                int4v pw;
                { unsigned a = __shfl(w0v[qq][t0], srcA), bx = __shfl(w0v[qq][t1], srcA);
                  pw.x = selhi ? (int)bx : (int)a; }
                { unsigned a = __shfl(w1v[qq][t0], srcA), bx = __shfl(w1v[qq][t1], srcA);
                  pw.y = selhi ? (int)bx : (int)a; }
                { unsigned a = __shfl(w0v[qq][t0], srcB), bx = __shfl(w0v[qq][t1], srcB);
                  pw.z = selhi ? (int)bx : (int)a; }
                { unsigned a = __shfl(w1v[qq][t0], srcB), bx = __shfl(w1v[qq][t1], srcB);
                  pw.w = selhi ? (int)bx : (int)a; }
                pf[qq] = __builtin_bit_cast(short8, pw);
            }
            #pragma unroll
            for (int mt = 0; mt < NMT; ++mt) {
                short8 vf = *(const short8*)(vbase + (((size_t)kt*NMT + mt)*2 + ks2)*512 + lane8);
                #pragma unroll
                for (int qq = 0; qq < NQ; ++qq)
                    acc[qq][mt] = __builtin_amdgcn_mfma_f32_16x16x32_bf16(vf, pf[qq], acc[qq][mt], 0, 0, 0);
            }
        }
    }

    // ---- finalize denominators: reduce across q4 groups
    #pragma unroll
    for (int qq = 0; qq < NQ; ++qq) {
        l_lane[qq] += __shfl_xor(l_lane[qq], 16);
        l_lane[qq] += __shfl_xor(l_lane[qq], 32);
        if (q4 == 0) lbuf[wave][qq*16 + n16] = l_lane[qq];
    }

    // ---- publish O^T partials
    if (MODE == 0) {
        float (&oSf)[NW][NQ*16][D + 1] = *reinterpret_cast<float (*)[NW][NQ*16][D + 1]>(oS_raw);
        #pragma unroll
        for (int qq = 0; qq < NQ; ++qq)
            #pragma unroll
            for (int mt = 0; mt < NMT; ++mt)
                #pragma unroll
                for (int r = 0; r < 4; ++r)
                    oSf[wave][qq*16 + n16][mt*16 + q4*4 + r] = acc[qq][mt][r];
    } else {
        unsigned short (&oSh)[NW][NQ*16][D + 2] =
            *reinterpret_cast<unsigned short (*)[NW][NQ*16][D + 2]>(oS_raw);
        #pragma unroll
        for (int qq = 0; qq < NQ; ++qq)
            #pragma unroll
            for (int mt = 0; mt < NMT; ++mt)
                #pragma unroll
                for (int r = 0; r < 4; ++r)
                    oSh[wave][qq*16 + n16][mt*16 + q4*4 + r] = (unsigned short)bfbits(acc[qq][mt][r]);
    }
    __syncthreads();  // single barrier: merge reads all splits

    if (MODE == 0) {
        // merge + ReLU per q-tile. Waves 0-3 merge; lane -> query (wave&3)*4+(lane>>4),
        // dims (lane&15)*2..+1
        float (&oSf)[NW][NQ*16][D + 1] = *reinterpret_cast<float (*)[NW][NQ*16][D + 1]>(oS_raw);
        if (wave < 4) {
            const int ql = (wave & 3)*4 + (lane >> 4);
            const int d2 = (lane & 15)*2;
            #pragma unroll
            for (int qq = 0; qq < NQ; ++qq) {
                const int row = qq*16 + ql;
                float denom = 0.f, o0 = 0.f, o1 = 0.f;
                #pragma unroll
                for (int s = 0; s < NW; ++s) {
                    denom += lbuf[s][row];
                    o0 += oSf[s][row][d2];
                    o1 += oSf[s][row][d2 + 1];
                }
                float di = 1.f / denom;
                unsigned w = bfbits(fmaxf(o0*di, 0.f)) | (bfbits(fmaxf(o1*di, 0.f)) << 16);
                *(unsigned*)&hout[((size_t)b*NN + q0 + row)*DOUT + hd*32 + d2] = w;
            }
        }
    } else {
        // merge + residual + LayerNorm per q-tile: lane handles query wave*2+(lane>>5),
        // dims (lane&31)*4..+3; row reduction via shfl_xor 16..1.
        unsigned short (&oSh)[NW][NQ*16][D + 2] =
            *reinterpret_cast<unsigned short (*)[NW][NQ*16][D + 2]>(oS_raw);
        const int ql = wave*2 + (lane >> 5);
        const int il = lane & 31;
        #pragma unroll
        for (int qq = 0; qq < NQ; ++qq) {
            const int row = qq*16 + ql;
            float denom = 0.f;
            #pragma unroll
            for (int s = 0; s < NW; ++s) denom += lbuf[s][row];
            float di = 1.f / denom;
            size_t base = ((size_t)b*NN + q0 + row)*DOUT + il*4;
            float4 pr = *(const float4*)(proj + base);
            float y[4];
            #pragma unroll
            for (int c = 0; c < 4; ++c) {
                float o = 0.f;
                #pragma unroll
                for (int s = 0; s < NW; ++s)
                    o += __uint_as_float(((unsigned)oSh[s][row][il*4 + c]) << 16);
                y[c] = o*di + ((const float*)&pr)[c];
            }
            float ssum = y[0] + y[1] + y[2] + y[3];
            #pragma unroll
            for (int off = 16; off >= 1; off >>= 1) ssum += __shfl_xor(ssum, off);
            float mu = ssum * (1.f/128.f);
            float vs = 0.f;
            #pragma unroll
            for (int c = 0; c < 4; ++c) { float d = y[c] - mu; vs += d*d; }
            #pragma unroll
            for (int off = 16; off >= 1; off >>= 1) vs += __shfl_xor(vs, off);
            float rs = rsqrtf(vs * (1.f/128.f) + 1e-3f);
            float4 g4 = *(const float4*)(lng + il*4);
            float4 b4 = *(const float4*)(lnb + il*4);
            float4 o4;
            #pragma unroll
            for (int c = 0; c < 4; ++c) {
                float o = (y[c] - mu)*rs*((const float*)&g4)[c] + ((const float*)&b4)[c];
                if (!(o == o)) o = 12345.0f;  // NaN sentinel (never hit on a passing run)
                ((float*)&o4)[c] = o;
            }
            *(float4*)(fout + base) = o4;
        }
    }
}

extern "C" void kernel_launch(void* const* d_in, const int* in_sizes, int n_in,
                              void* d_out, int out_size, void* d_ws, size_t ws_size,
                              hipStream_t stream)
{
    const float* x   = (const float*)d_in[0];
    // d_in[1] = emb is dead: adj = sigmoid(l2norm(emb)@l2norm(emb)^T) in [0.27,1],
    // diag forced 1 -> adj==0 never true -> dense attention.
    const float* q1w = (const float*)d_in[2];
    const float* q1b = (const float*)d_in[3];
    const float* k1w = (const float*)d_in[4];
    const float* k1b = (const float*)d_in[5];
    const float* v1w = (const float*)d_in[6];
    const float* v1b = (const float*)d_in[7];
    const float* q2w = (const float*)d_in[8];
    const float* q2b = (const float*)d_in[9];
    const float* k2w = (const float*)d_in[10];
    const float* k2b = (const float*)d_in[11];
    const float* v2w = (const float*)d_in[12];
    const float* v2b = (const float*)d_in[13];
    const float* pw  = (const float*)d_in[14];
    const float* lng = (const float*)d_in[15];
    const float* lnb = (const float*)d_in[16];

    // Workspace: 12 MB (proven). q/k/vT slots reused across the two layers.
    const size_t SZ = (size_t)NB*NN*DOUT;           // 1,048,576 elements
    char* wsb = (char*)d_ws;
    bf16*  qA   = (bf16*)(wsb + 0*SZ*2);            // 2 MB (fragment-linear)
    bf16*  kA   = (bf16*)(wsb + 1*SZ*2);            // 2 MB (fragment-linear)
    bf16*  vT   = (bf16*)(wsb + 2*SZ*2);            // 2 MB (fragment-linear)
    float* proj = (float*)(wsb + 3*SZ*2);           // 4 MB
    bf16*  h    = (bf16*)(wsb + 3*SZ*2 + SZ*4);     // 2 MB (row-major)

    k_gemm1<<<dim3(128, 8), 256, 0, stream>>>(x, q1w, q1b, k1w, k1b, v1w, v1b, pw,
                                              qA, kA, vT, proj);
    // MODE0: NQ=4, NW=8 -> 512 blocks, 512 threads
    k_attn_mfma<32, 0, 8, 4><<<dim3(32, 16), 512, 0, stream>>>(
        qA, kA, vT, nullptr, nullptr, nullptr, h, nullptr);
    k_gemm2<<<dim3(128, 6), 256, 0, stream>>>(h, q2w, q2b, k2w, k2b, v2w, v2b,
                                              qA, kA, vT);
    // MODE1: NQ=2, NW=8 -> 256 blocks, 512 threads
    k_attn_mfma<128, 1, 8, 2><<<dim3(64, 4), 512, 0, stream>>>(
        qA, kA, vT, proj, lng, lnb, nullptr, (float*)d_out);
}